// Round 1
// baseline (1213.453 us; speedup 1.0000x reference)
//
#include <hip/hip_runtime.h>
#include <math.h>

#define DIM   1024
#define NHEAD 16
#define HD    64
#define SEQ   2048
#define BATCH 2
#define MROWS (BATCH * SEQ)   // 4096

// ---------------- RoPE cos/sin table: [SEQ][32] of (cos, sin) ----------------
// Mimic the reference's fp32 arithmetic: freq = 10000^(-2i/64) in fp32,
// angle = s * freq in fp32, then precise sin/cos of that fp32 angle.
__global__ __launch_bounds__(256) void rope_table_kernel(float2* __restrict__ tbl) {
    int idx = blockIdx.x * 256 + threadIdx.x;     // 0..65535
    int s = idx >> 5, i = idx & 31;
    float freq = powf(10000.0f, -(float)(2 * i) * (1.0f / 64.0f));
    float ang  = (float)s * freq;
    tbl[idx] = make_float2(cosf(ang), sinf(ang));
}

// ---------------- GEMM NT: C[M,N] = A[M,K] * B[N,K]^T  (all row-major) -------
// BM=BN=128, BK=16, 256 threads, 8x8 micro-tile in 2x2 quadrants of 4x4.
// As/Bs stored transposed [BK][BM+4]; +4 pad keeps float4 reads 16B-aligned
// and spreads the transposed scatter-writes across banks (<=2-way).
__device__ __forceinline__ void gemm_nt_tile(const float* __restrict__ A,
                                             const float* __restrict__ B,
                                             float* __restrict__ C,
                                             float (*As)[132], float (*Bs)[132]) {
    const int K = DIM, N = DIM;
    const int tid = threadIdx.x;
    const int ty = tid >> 4, tx = tid & 15;
    const int rowBase = blockIdx.y * 128;
    const int colBase = blockIdx.x * 128;

    float acc[8][8];
#pragma unroll
    for (int i = 0; i < 8; ++i)
#pragma unroll
        for (int j = 0; j < 8; ++j) acc[i][j] = 0.0f;

    for (int kt = 0; kt < K / 16; ++kt) {
        // Stage 128x16 tiles of A and B, transposed into [k][row] layout.
        // Loader: 4 rows x 64B contiguous per wave -> decent coalescing.
#pragma unroll
        for (int l = 0; l < 2; ++l) {
            int linear = tid + l * 256;           // 0..511
            int row = linear >> 2;                // 0..127
            int c4  = (linear & 3) << 2;          // 0,4,8,12
            float4 av = *(const float4*)(A + (size_t)(rowBase + row) * K + kt * 16 + c4);
            As[c4 + 0][row] = av.x; As[c4 + 1][row] = av.y;
            As[c4 + 2][row] = av.z; As[c4 + 3][row] = av.w;
            float4 bv = *(const float4*)(B + (size_t)(colBase + row) * K + kt * 16 + c4);
            Bs[c4 + 0][row] = bv.x; Bs[c4 + 1][row] = bv.y;
            Bs[c4 + 2][row] = bv.z; Bs[c4 + 3][row] = bv.w;
        }
        __syncthreads();
#pragma unroll
        for (int kk = 0; kk < 16; ++kk) {
            float4 a0 = *(const float4*)&As[kk][ty * 4];
            float4 a1 = *(const float4*)&As[kk][64 + ty * 4];
            float4 b0 = *(const float4*)&Bs[kk][tx * 4];
            float4 b1 = *(const float4*)&Bs[kk][64 + tx * 4];
            float a[8] = {a0.x, a0.y, a0.z, a0.w, a1.x, a1.y, a1.z, a1.w};
            float b[8] = {b0.x, b0.y, b0.z, b0.w, b1.x, b1.y, b1.z, b1.w};
#pragma unroll
            for (int i = 0; i < 8; ++i)
#pragma unroll
                for (int j = 0; j < 8; ++j)
                    acc[i][j] = fmaf(a[i], b[j], acc[i][j]);
        }
        __syncthreads();
    }

#pragma unroll
    for (int ig = 0; ig < 2; ++ig)
#pragma unroll
        for (int i = 0; i < 4; ++i) {
            int r = rowBase + ig * 64 + ty * 4 + i;
#pragma unroll
            for (int jg = 0; jg < 2; ++jg) {
                int c = colBase + jg * 64 + tx * 4;
                float4 v = make_float4(acc[ig * 4 + i][jg * 4 + 0], acc[ig * 4 + i][jg * 4 + 1],
                                       acc[ig * 4 + i][jg * 4 + 2], acc[ig * 4 + i][jg * 4 + 3]);
                *(float4*)(C + (size_t)r * N + c) = v;
            }
        }
}

__global__ __launch_bounds__(256) void gemm_qkv_kernel(const float* __restrict__ X,
                                                       const float* __restrict__ Wq,
                                                       const float* __restrict__ Wk,
                                                       const float* __restrict__ Wv,
                                                       float* __restrict__ Q,
                                                       float* __restrict__ Kb,
                                                       float* __restrict__ V) {
    __shared__ float As[16][132];
    __shared__ float Bs[16][132];
    const float* B = (blockIdx.z == 0) ? Wq : (blockIdx.z == 1) ? Wk : Wv;
    float* C       = (blockIdx.z == 0) ? Q  : (blockIdx.z == 1) ? Kb : V;
    gemm_nt_tile(X, B, C, As, Bs);
}

__global__ __launch_bounds__(256) void gemm_out_kernel(const float* __restrict__ AO,
                                                       const float* __restrict__ Wo,
                                                       float* __restrict__ OUT) {
    __shared__ float As[16][132];
    __shared__ float Bs[16][132];
    gemm_nt_tile(AO, Wo, OUT, As, Bs);
}

// ---------------- RoPE (in-place on Q and K) ----------------
__global__ __launch_bounds__(256) void rope_kernel(float* __restrict__ Q,
                                                   float* __restrict__ K,
                                                   const float2* __restrict__ tbl) {
    int idx = blockIdx.x * 256 + threadIdx.x;   // 0 .. MROWS*512-1
    float* X = blockIdx.y ? K : Q;
    int m = idx >> 9;            // row in [0, 4096)
    int p = idx & 511;           // pair index within row
    int h = p >> 5, i = p & 31;  // head, dim-pair
    int s = m & (SEQ - 1);       // position
    float2 cs = tbl[(s << 5) + i];
    size_t base = (size_t)m * DIM + h * HD + i;
    float x0 = X[base], x1 = X[base + 32];
    X[base]      = fmaf(x0, cs.x, -x1 * cs.y);   // x0*cos - x1*sin
    X[base + 32] = fmaf(x1, cs.x,  x0 * cs.y);   // x1*cos + x0*sin
}

// ---------------- flash attention ----------------
// One block per (b, h, 64-row q-tile). 256 threads; thread (ty,tx) owns a
// 4x4 micro-tile of the 64x64 score / output tiles. K/Q/P tiles use an XOR
// swizzle (col ^= ((row>>2)&7)<<2) so the 16-lane consecutive-row reads
// (stride 256B -> single bank group unswizzled) are conflict-free.
__global__ __launch_bounds__(256) void attn_kernel(const float* __restrict__ Q,
                                                   const float* __restrict__ K,
                                                   const float* __restrict__ V,
                                                   float* __restrict__ O) {
    __shared__ __align__(16) float Qs[64][64];
    __shared__ __align__(16) float Ks[64][64];
    __shared__ __align__(16) float Vs[64][64];
    __shared__ __align__(16) float Ps[64][64];

    const int tid = threadIdx.x;
    const int ty = tid >> 4, tx = tid & 15;
    const int qt = blockIdx.x, h = blockIdx.y, b = blockIdx.z;

    const float* Qp = Q + ((size_t)b * SEQ + qt * 64) * DIM + h * HD;
    const float* Kp = K + ((size_t)b * SEQ) * DIM + h * HD;
    const float* Vp = V + ((size_t)b * SEQ) * DIM + h * HD;
    float* Op       = O + ((size_t)b * SEQ + qt * 64) * DIM + h * HD;

    // Load Q tile once, pre-scaled by 1/sqrt(64) = 0.125, swizzled.
#pragma unroll
    for (int l = 0; l < 4; ++l) {
        int linear = tid + l * 256;
        int row = linear >> 4;
        int c4  = (linear & 15) << 2;
        float4 v = *(const float4*)(Qp + (size_t)row * DIM + c4);
        v.x *= 0.125f; v.y *= 0.125f; v.z *= 0.125f; v.w *= 0.125f;
        int cs = c4 ^ (((row >> 2) & 7) << 2);
        *(float4*)&Qs[row][cs] = v;
    }

    float o[4][4];
    float mrun[4], lrun[4];
#pragma unroll
    for (int i = 0; i < 4; ++i) {
        mrun[i] = -INFINITY; lrun[i] = 0.0f;
#pragma unroll
        for (int j = 0; j < 4; ++j) o[i][j] = 0.0f;
    }

    const int xq = (ty & 7) << 2;   // swizzle for this thread's q-rows (ty*4+i)>>2 == ty
    const int xk = (tx & 7) << 2;   // swizzle for this thread's k-rows (tx*4+j)>>2 == tx

    for (int kt = 0; kt < SEQ / 64; ++kt) {
        // Stage K (swizzled) and V (plain row-major) tiles.
#pragma unroll
        for (int l = 0; l < 4; ++l) {
            int linear = tid + l * 256;
            int row = linear >> 4;
            int c4  = (linear & 15) << 2;
            int cs  = c4 ^ (((row >> 2) & 7) << 2);
            float4 kv = *(const float4*)(Kp + (size_t)(kt * 64 + row) * DIM + c4);
            *(float4*)&Ks[row][cs] = kv;
            float4 vv = *(const float4*)(Vp + (size_t)(kt * 64 + row) * DIM + c4);
            *(float4*)&Vs[row][c4] = vv;
        }
        __syncthreads();

        // Scores: s[i][j] = q_row(ty*4+i) . k_row(tx*4+j)   (Q pre-scaled)
        float s[4][4];
#pragma unroll
        for (int i = 0; i < 4; ++i)
#pragma unroll
            for (int j = 0; j < 4; ++j) s[i][j] = 0.0f;

#pragma unroll
        for (int d4 = 0; d4 < 64; d4 += 4) {
            float4 aq[4], bk[4];
#pragma unroll
            for (int i = 0; i < 4; ++i)
                aq[i] = *(const float4*)&Qs[ty * 4 + i][d4 ^ xq];
#pragma unroll
            for (int j = 0; j < 4; ++j)
                bk[j] = *(const float4*)&Ks[tx * 4 + j][d4 ^ xk];
#pragma unroll
            for (int i = 0; i < 4; ++i)
#pragma unroll
                for (int j = 0; j < 4; ++j) {
                    s[i][j] = fmaf(aq[i].x, bk[j].x, s[i][j]);
                    s[i][j] = fmaf(aq[i].y, bk[j].y, s[i][j]);
                    s[i][j] = fmaf(aq[i].z, bk[j].z, s[i][j]);
                    s[i][j] = fmaf(aq[i].w, bk[j].w, s[i][j]);
                }
        }

        // Online softmax (row stats replicated across the 16 tx lanes of a row group).
        float p[4][4];
#pragma unroll
        for (int i = 0; i < 4; ++i) {
            float tm = fmaxf(fmaxf(s[i][0], s[i][1]), fmaxf(s[i][2], s[i][3]));
#pragma unroll
            for (int off = 1; off < 16; off <<= 1)
                tm = fmaxf(tm, __shfl_xor(tm, off, 16));
            float mn = fmaxf(mrun[i], tm);
            float alpha = __expf(mrun[i] - mn);   // exp(-inf - finite) = 0 on first tile
            float rs = 0.0f;
#pragma unroll
            for (int j = 0; j < 4; ++j) {
                p[i][j] = __expf(s[i][j] - mn);
                rs += p[i][j];
            }
#pragma unroll
            for (int off = 1; off < 16; off <<= 1)
                rs += __shfl_xor(rs, off, 16);
            lrun[i] = lrun[i] * alpha + rs;
            mrun[i] = mn;
#pragma unroll
            for (int j = 0; j < 4; ++j) o[i][j] *= alpha;
        }

        // Write P tile (swizzled with the q-row swizzle).
#pragma unroll
        for (int i = 0; i < 4; ++i)
            *(float4*)&Ps[ty * 4 + i][(tx * 4) ^ xq] =
                make_float4(p[i][0], p[i][1], p[i][2], p[i][3]);
        __syncthreads();

        // PV: o[i][j] += P[row_i][k] * V[k][col_j], k blocked by 4 for b128 reads.
#pragma unroll
        for (int k4 = 0; k4 < 64; k4 += 4) {
            float pr[4][4];
#pragma unroll
            for (int i = 0; i < 4; ++i) {
                float4 t = *(const float4*)&Ps[ty * 4 + i][k4 ^ xq];
                pr[i][0] = t.x; pr[i][1] = t.y; pr[i][2] = t.z; pr[i][3] = t.w;
            }
#pragma unroll
            for (int t = 0; t < 4; ++t) {
                float4 v4 = *(const float4*)&Vs[k4 + t][tx * 4];
#pragma unroll
                for (int i = 0; i < 4; ++i) {
                    o[i][0] = fmaf(pr[i][t], v4.x, o[i][0]);
                    o[i][1] = fmaf(pr[i][t], v4.y, o[i][1]);
                    o[i][2] = fmaf(pr[i][t], v4.z, o[i][2]);
                    o[i][3] = fmaf(pr[i][t], v4.w, o[i][3]);
                }
            }
        }
        __syncthreads();   // protect Ks/Vs/Ps before next iteration's staging
    }

    // Normalize and store.
#pragma unroll
    for (int i = 0; i < 4; ++i) {
        float inv = 1.0f / lrun[i];
        float4 v = make_float4(o[i][0] * inv, o[i][1] * inv, o[i][2] * inv, o[i][3] * inv);
        *(float4*)(Op + (size_t)(ty * 4 + i) * DIM + tx * 4) = v;
    }
}

// ---------------- launch ----------------
extern "C" void kernel_launch(void* const* d_in, const int* in_sizes, int n_in,
                              void* d_out, int out_size, void* d_ws, size_t ws_size,
                              hipStream_t stream) {
    const float* x  = (const float*)d_in[0];
    const float* Wq = (const float*)d_in[1];
    const float* Wk = (const float*)d_in[2];
    const float* Wv = (const float*)d_in[3];
    const float* Wo = (const float*)d_in[4];
    float* out = (float*)d_out;

    // Workspace layout: Q | K | V | attn_out (16 MB each) | rope table (512 KB).
    char* ws = (char*)d_ws;
    const size_t BUF = (size_t)MROWS * DIM * sizeof(float);   // 16 MB
    float*  Q   = (float*)(ws);
    float*  K   = (float*)(ws + BUF);
    float*  V   = (float*)(ws + 2 * BUF);
    float*  AO  = (float*)(ws + 3 * BUF);
    float2* tbl = (float2*)(ws + 4 * BUF);

    rope_table_kernel<<<256, 256, 0, stream>>>(tbl);

    dim3 gqkv(DIM / 128, MROWS / 128, 3);                      // 8 x 32 x 3
    gemm_qkv_kernel<<<gqkv, 256, 0, stream>>>(x, Wq, Wk, Wv, Q, K, V);

    rope_kernel<<<dim3(MROWS * 512 / 256, 2), 256, 0, stream>>>(Q, K, tbl);

    attn_kernel<<<dim3(SEQ / 64, NHEAD, BATCH), 256, 0, stream>>>(Q, K, V, AO);

    gemm_out_kernel<<<dim3(DIM / 128, MROWS / 128), 256, 0, stream>>>(AO, Wo, out);
}

// Round 5
// 338.696 us; speedup vs baseline: 3.5827x; 3.5827x over previous
//
#include <hip/hip_runtime.h>

#define DIM   1024
#define NHEAD 16
#define HD    64
#define SEQ   2048
#define BATCH 2
#define MROWS (BATCH * SEQ)   // 4096
#define NT    (SEQ / 64)      // 32 KV tiles

typedef __attribute__((ext_vector_type(8))) _Float16 s8h;   // 8 f16 in 4 VGPRs
typedef __attribute__((ext_vector_type(4))) _Float16 s4h;   // 4 f16 (8B)
typedef __attribute__((ext_vector_type(4))) float f32x4;

typedef const __attribute__((address_space(1))) unsigned GU;
typedef __attribute__((address_space(3))) unsigned LU;

__device__ __forceinline__ void gll16(const void* g, void* l) {
    // async global->LDS, 16B/lane; LDS dest = wave-uniform base + lane*16
    __builtin_amdgcn_global_load_lds((GU*)g, (LU*)l, 16, 0, 0);
}
__device__ __forceinline__ f32x4 mfma16(s8h a, s8h b, f32x4 c) {
    return __builtin_amdgcn_mfma_f32_16x16x32_f16(a, b, c, 0, 0, 0);
}
// 2^x via v_exp_f32. NOTE: not named __exp2f (glibc owns that symbol).
__device__ __forceinline__ float ex2(float x) {
    return __builtin_amdgcn_exp2f(x);
}

// ---------------- fp32 -> fp16 cast: x | Wq | Wk | Wv | Wo ----------------
__global__ __launch_bounds__(256) void cast_f16_kernel(
    const float* __restrict__ x,  const float* __restrict__ wq,
    const float* __restrict__ wk, const float* __restrict__ wv,
    const float* __restrict__ wo,
    _Float16* __restrict__ xh,  _Float16* __restrict__ wqh,
    _Float16* __restrict__ wkh, _Float16* __restrict__ wvh,
    _Float16* __restrict__ woh) {
    int id = blockIdx.x * 256 + threadIdx.x;   // 1,048,576 threads x 8 elems
    const float* src; _Float16* dst; size_t off;
    if (id < 524288) { src = x; dst = xh; off = (size_t)id * 8; }
    else {
        int r = id - 524288, w = r >> 17, o = r & 131071;
        src = (w == 0) ? wq : (w == 1) ? wk : (w == 2) ? wv : wo;
        dst = (w == 0) ? wqh : (w == 1) ? wkh : (w == 2) ? wvh : woh;
        off = (size_t)o * 8;
    }
    float4 v0 = *(const float4*)(src + off);
    float4 v1 = *(const float4*)(src + off + 4);
    s8h y;
    y[0]=(_Float16)v0.x; y[1]=(_Float16)v0.y; y[2]=(_Float16)v0.z; y[3]=(_Float16)v0.w;
    y[4]=(_Float16)v1.x; y[5]=(_Float16)v1.y; y[6]=(_Float16)v1.z; y[7]=(_Float16)v1.w;
    *(s8h*)(dst + off) = y;
}

// ---------------- RoPE cos/sin table [SEQ][32] float2 ----------------
__global__ __launch_bounds__(256) void rope_table_kernel(float2* __restrict__ tbl) {
    int idx = blockIdx.x * 256 + threadIdx.x;     // 65536
    int s = idx >> 5, i = idx & 31;
    float freq = powf(10000.0f, -(float)(2 * i) * (1.0f / 64.0f));
    float ang  = (float)s * freq;
    tbl[idx] = make_float2(cosf(ang), sinf(ang));
}

// ---------------- f16 GEMM NT: C[rb+128][cb+128] = A*B^T, K=DIM -----------
// m97-proven structure: 128x128 tile, BK=64, 4 waves (2x2 of 64x64),
// LINEAR LDS [128][64] staged by global_load_lds (no swizzle; T2 null at 2ph).
template <bool F32OUT>
__device__ __forceinline__ void gemm_core(const _Float16* __restrict__ A,
                                          const _Float16* __restrict__ Bw,
                                          void* __restrict__ C, int ldc,
                                          int rowBase, int colBase) {
    __shared__ _Float16 As[128][64];
    __shared__ _Float16 Bs[128][64];
    const int tid = threadIdx.x, wid = tid >> 6, l = tid & 63;
    const int g = l >> 4, li = l & 15;
    const int wr = wid >> 1, wc = wid & 1;

    f32x4 acc[4][4];
#pragma unroll
    for (int m = 0; m < 4; ++m)
#pragma unroll
        for (int n = 0; n < 4; ++n) acc[m][n] = (f32x4){0.f, 0.f, 0.f, 0.f};

    const int srow = l >> 3;       // row within 8-row chunk
    const int schunk = l & 7;      // 16B chunk within row (LINEAR)

    for (int kt = 0; kt < DIM / 64; ++kt) {
#pragma unroll
        for (int i = 0; i < 4; ++i) {
            int c = wid * 4 + i;
            gll16(A  + (size_t)(rowBase + c * 8 + srow) * DIM + kt * 64 + schunk * 8, &As[c * 8][0]);
            gll16(Bw + (size_t)(colBase + c * 8 + srow) * DIM + kt * 64 + schunk * 8, &Bs[c * 8][0]);
        }
        __syncthreads();
        s8h a[4][2], b[4][2];
#pragma unroll
        for (int m = 0; m < 4; ++m) {
            int row = wr * 64 + m * 16 + li;
            a[m][0] = *(const s8h*)&As[row][g * 8];
            a[m][1] = *(const s8h*)&As[row][32 + g * 8];
        }
#pragma unroll
        for (int n = 0; n < 4; ++n) {
            int col = wc * 64 + n * 16 + li;
            b[n][0] = *(const s8h*)&Bs[col][g * 8];
            b[n][1] = *(const s8h*)&Bs[col][32 + g * 8];
        }
#pragma unroll
        for (int m = 0; m < 4; ++m)
#pragma unroll
            for (int n = 0; n < 4; ++n) {
                acc[m][n] = mfma16(a[m][0], b[n][0], acc[m][n]);
                acc[m][n] = mfma16(a[m][1], b[n][1], acc[m][n]);
            }
        __syncthreads();
    }
#pragma unroll
    for (int m = 0; m < 4; ++m)
#pragma unroll
        for (int n = 0; n < 4; ++n)
#pragma unroll
            for (int j = 0; j < 4; ++j) {
                int r = rowBase + wr * 64 + m * 16 + g * 4 + j;
                int c = colBase + wc * 64 + n * 16 + li;
                if (F32OUT) ((float*)C)[(size_t)r * ldc + c] = acc[m][n][j];
                else        ((_Float16*)C)[(size_t)r * ldc + c] = (_Float16)acc[m][n][j];
            }
}

// z=0: Q = X Wq^T   z=1: K = X Wk^T   z=2: V^T = Wv X^T (ldc = MROWS)
__global__ __launch_bounds__(256) void gemm_qkv_kernel(
    const _Float16* __restrict__ X,
    const _Float16* __restrict__ Wq, const _Float16* __restrict__ Wk,
    const _Float16* __restrict__ Wv,
    _Float16* __restrict__ Q, _Float16* __restrict__ K,
    _Float16* __restrict__ Vt) {
    if (blockIdx.z == 2) {
        // C[d][r] over 1024 x 4096: rowBase from x (8 tiles), colBase from y (32)
        gemm_core<false>(Wv, X, Vt, MROWS, blockIdx.x * 128, blockIdx.y * 128);
    } else {
        const _Float16* B = (blockIdx.z == 0) ? Wq : Wk;
        _Float16* C       = (blockIdx.z == 0) ? Q  : K;
        gemm_core<false>(X, B, C, DIM, blockIdx.y * 128, blockIdx.x * 128);
    }
}
__global__ __launch_bounds__(256) void gemm_out_kernel(
    const _Float16* __restrict__ AO, const _Float16* __restrict__ Wo,
    float* __restrict__ OUT) {
    gemm_core<true>(AO, Wo, OUT, DIM, blockIdx.y * 128, blockIdx.x * 128);
}

// ---------------- RoPE on fp16 Q,K (in place) ----------------
__global__ __launch_bounds__(256) void rope_f16_kernel(_Float16* __restrict__ Q,
                                                       _Float16* __restrict__ K,
                                                       const float2* __restrict__ tbl) {
    int id = blockIdx.x * 256 + threadIdx.x;   // [2][4096][16][4]
    int c = id & 3, h = (id >> 2) & 15, row = (id >> 6) & 4095;
    _Float16* X = (id >> 18) ? K : Q;
    int s = row & (SEQ - 1);
    size_t base = (size_t)row * DIM + h * HD + c * 8;
    s8h x1 = *(const s8h*)(X + base);
    s8h x2 = *(const s8h*)(X + base + 32);
    const float4* tp = (const float4*)(tbl + s * 32 + c * 8);
    float4 t0 = tp[0], t1 = tp[1], t2 = tp[2], t3 = tp[3];
    float cs[8] = {t0.x, t0.z, t1.x, t1.z, t2.x, t2.z, t3.x, t3.z};
    float sn[8] = {t0.y, t0.w, t1.y, t1.w, t2.y, t2.w, t3.y, t3.w};
    s8h y1, y2;
#pragma unroll
    for (int e = 0; e < 8; ++e) {
        float a = (float)x1[e], bq = (float)x2[e];
        y1[e] = (_Float16)fmaf(a, cs[e], -bq * sn[e]);
        y2[e] = (_Float16)fmaf(bq, cs[e],  a * sn[e]);
    }
    *(s8h*)(X + base)      = y1;
    *(s8h*)(X + base + 32) = y2;
}

// ---------------- flash attention: LDS-free, barrier-free, fp16 MFMA ------
// 256 thr = 4 waves, each wave independent: 32 q-rows (2 n-tiles of 16).
// S^T = mfma(A=K, B=Q): lane (g,li) holds S^T[mt*16+g*4+jj][nt*16+li]
//   (C/D map m89: row = g*4+reg, col = li) -> softmax = in-lane + 2 shuffles.
// PV: O^T = mfma(A=V^T, B=P^T). Shared k-order kappa(g,kc,e) =
//   kc*32 + (e>>2)*16 + g*4 + (e&3). A-slot e loads V^T[d][kt*64+kappa]
//   (two contiguous 8B loads); B-slot e = st[kc*2+(e>>2)][nt][e&3] (lane-local).
//   Slot-wise consistency => HW's internal k map cancels.
__global__ __launch_bounds__(256, 2) void attn_kernel(const _Float16* __restrict__ Q,
                                                      const _Float16* __restrict__ K,
                                                      const _Float16* __restrict__ Vt,
                                                      _Float16* __restrict__ AO) {
    const int tid = threadIdx.x, wid = tid >> 6, l = tid & 63;
    const int g = l >> 4, li = l & 15;
    const int qt = blockIdx.x, h = blockIdx.y, b = blockIdx.z;

    const _Float16* Qh  = Q  + ((size_t)(b * SEQ) + qt * 128 + wid * 32) * DIM + h * HD;
    const _Float16* Kh  = K  + (size_t)(b * SEQ) * DIM + h * HD;
    const _Float16* Vth = Vt + (size_t)(h * HD) * MROWS + b * SEQ;
    _Float16* AOh = AO + ((size_t)(b * SEQ) + qt * 128 + wid * 32) * DIM + h * HD;

    // Q fragments: Q[q=nt*16+li][d=dc*32+g*8+e]
    s8h qf[2][2];
#pragma unroll
    for (int nt = 0; nt < 2; ++nt)
#pragma unroll
        for (int dc = 0; dc < 2; ++dc)
            qf[nt][dc] = *(const s8h*)(Qh + (size_t)(nt * 16 + li) * DIM + dc * 32 + g * 8);

    f32x4 o[4][2];                 // O^T[d=mtd*16+g*4+jj][q=nt*16+li]
    float mrun[2], lrun[2];
#pragma unroll
    for (int nt = 0; nt < 2; ++nt) { mrun[nt] = -INFINITY; lrun[nt] = 0.f; }
#pragma unroll
    for (int mtd = 0; mtd < 4; ++mtd)
#pragma unroll
        for (int nt = 0; nt < 2; ++nt) o[mtd][nt] = (f32x4){0.f, 0.f, 0.f, 0.f};

    const float C1 = 0.125f * 1.44269504088896f;   // 1/sqrt(64) * log2(e)

    for (int kt = 0; kt < NT; ++kt) {
        // ---- S^T = K * Q^T (K frags straight from global/L2) ----
        f32x4 st[4][2];
#pragma unroll
        for (int mt = 0; mt < 4; ++mt)
#pragma unroll
            for (int nt = 0; nt < 2; ++nt) st[mt][nt] = (f32x4){0.f, 0.f, 0.f, 0.f};
#pragma unroll
        for (int mt = 0; mt < 4; ++mt) {
            const _Float16* kp = Kh + (size_t)(kt * 64 + mt * 16 + li) * DIM + g * 8;
            s8h k0 = *(const s8h*)(kp);
            s8h k1 = *(const s8h*)(kp + 32);
#pragma unroll
            for (int nt = 0; nt < 2; ++nt) {
                st[mt][nt] = mfma16(k0, qf[nt][0], st[mt][nt]);
                st[mt][nt] = mfma16(k1, qf[nt][1], st[mt][nt]);
            }
        }

        // ---- V^T fragments: issue early so latency hides under softmax ----
        s4h va[4][2][2];
#pragma unroll
        for (int mtd = 0; mtd < 4; ++mtd)
#pragma unroll
            for (int kc = 0; kc < 2; ++kc) {
                const _Float16* vp =
                    Vth + (size_t)(mtd * 16 + li) * MROWS + kt * 64 + kc * 32 + g * 4;
                va[mtd][kc][0] = *(const s4h*)(vp);
                va[mtd][kc][1] = *(const s4h*)(vp + 16);
            }

        // ---- online softmax per q-col (nt,li); kpos spread over mt,g,jj ----
#pragma unroll
        for (int nt = 0; nt < 2; ++nt) {
            float tm = st[0][nt][0];
#pragma unroll
            for (int mt = 0; mt < 4; ++mt)
#pragma unroll
                for (int jj = 0; jj < 4; ++jj)
                    if (mt || jj) tm = fmaxf(tm, st[mt][nt][jj]);
            tm = fmaxf(tm, __shfl_xor(tm, 16));
            tm = fmaxf(tm, __shfl_xor(tm, 32));
            float mo = mrun[nt];
            float mn = fmaxf(mo, tm);
            float alpha = ex2((mo - mn) * C1);
            float rs = 0.f;
#pragma unroll
            for (int mt = 0; mt < 4; ++mt)
#pragma unroll
                for (int jj = 0; jj < 4; ++jj) {
                    float p = ex2((st[mt][nt][jj] - mn) * C1);
                    st[mt][nt][jj] = p;
                    rs += p;
                }
            rs += __shfl_xor(rs, 16);
            rs += __shfl_xor(rs, 32);
            lrun[nt] = lrun[nt] * alpha + rs;
            mrun[nt] = mn;
#pragma unroll
            for (int mtd = 0; mtd < 4; ++mtd) {
                o[mtd][nt][0] *= alpha; o[mtd][nt][1] *= alpha;
                o[mtd][nt][2] *= alpha; o[mtd][nt][3] *= alpha;
            }
        }

        // ---- P^T -> f16 B-fragments in k-order kappa ----
        s8h pb[2][2];
#pragma unroll
        for (int nt = 0; nt < 2; ++nt)
#pragma unroll
            for (int kc = 0; kc < 2; ++kc)
#pragma unroll
                for (int e = 0; e < 8; ++e)
                    pb[nt][kc][e] = (_Float16)st[kc * 2 + (e >> 2)][nt][e & 3];

        // ---- O^T += V^T * P^T ----
#pragma unroll
        for (int mtd = 0; mtd < 4; ++mtd)
#pragma unroll
            for (int kc = 0; kc < 2; ++kc) {
                s8h v8;
#pragma unroll
                for (int e = 0; e < 4; ++e) { v8[e] = va[mtd][kc][0][e]; v8[4 + e] = va[mtd][kc][1][e]; }
#pragma unroll
                for (int nt = 0; nt < 2; ++nt)
                    o[mtd][nt] = mfma16(v8, pb[nt][kc], o[mtd][nt]);
            }
    }

    // ---- epilogue: normalize, 8B packed stores ----
#pragma unroll
    for (int nt = 0; nt < 2; ++nt) {
        float inv = 1.0f / lrun[nt];
#pragma unroll
        for (int mtd = 0; mtd < 4; ++mtd) {
            s4h w;
#pragma unroll
            for (int jj = 0; jj < 4; ++jj) w[jj] = (_Float16)(o[mtd][nt][jj] * inv);
            *(s4h*)(AOh + (size_t)(nt * 16 + li) * DIM + mtd * 16 + g * 4) = w;
        }
    }
}

// ---------------- launch ----------------
extern "C" void kernel_launch(void* const* d_in, const int* in_sizes, int n_in,
                              void* d_out, int out_size, void* d_ws, size_t ws_size,
                              hipStream_t stream) {
    const float* x  = (const float*)d_in[0];
    const float* Wq = (const float*)d_in[1];
    const float* Wk = (const float*)d_in[2];
    const float* Wv = (const float*)d_in[3];
    const float* Wo = (const float*)d_in[4];
    float* out = (float*)d_out;

    char* ws = (char*)d_ws;
    _Float16* xh  = (_Float16*)(ws);
    _Float16* Wqh = (_Float16*)(ws + 8388608);
    _Float16* Wkh = (_Float16*)(ws + 10485760);
    _Float16* Wvh = (_Float16*)(ws + 12582912);
    _Float16* Woh = (_Float16*)(ws + 14680064);
    _Float16* Qh  = (_Float16*)(ws + 16777216);
    _Float16* Kh  = (_Float16*)(ws + 25165824);
    _Float16* Vth = (_Float16*)(ws + 33554432);   // V^T [1024][4096]
    _Float16* AOh = (_Float16*)(ws + 41943040);
    float2*   tbl = (float2*)  (ws + 50331648);

    cast_f16_kernel<<<4096, 256, 0, stream>>>(x, Wq, Wk, Wv, Wo, xh, Wqh, Wkh, Wvh, Woh);
    rope_table_kernel<<<256, 256, 0, stream>>>(tbl);
    gemm_qkv_kernel<<<dim3(8, 32, 3), 256, 0, stream>>>(xh, Wqh, Wkh, Wvh, Qh, Kh, Vth);
    rope_f16_kernel<<<2048, 256, 0, stream>>>(Qh, Kh, tbl);
    attn_kernel<<<dim3(16, 16, 2), 256, 0, stream>>>(Qh, Kh, Vth, AOh);
    gemm_out_kernel<<<dim3(8, 32), 256, 0, stream>>>(AOh, Woh, out);
}